// Round 20
// baseline (666.902 us; speedup 1.0000x reference)
//
#include <hip/hip_runtime.h>
#include <cstdint>
#include <cstddef>

#define NN 50000
#define NE 400000
#define NG 256
#define DIM 200
#define NSTEPS 6
#define ROWU 256   // ushorts per state row (512B, line-aligned; 200 used)
#define ROWQ 32    // uint4 per state row

typedef unsigned int uint;
typedef unsigned short ushort;
typedef __attribute__((ext_vector_type(8))) short short8;
typedef __attribute__((ext_vector_type(4))) float f32x4;

#define GLL16(gsrc, ldst)                                                        \
  __builtin_amdgcn_global_load_lds(                                              \
      (const __attribute__((address_space(1))) void*)(gsrc),                     \
      (__attribute__((address_space(3))) void*)(ldst), 16, 0, 0)

__device__ __forceinline__ float bfu(ushort u) { return __uint_as_float((uint)u << 16); }
__device__ __forceinline__ ushort bf16rn(float v) {
  uint u = __float_as_uint(v);
  return (ushort)((u + 0x7fffu + ((u >> 16) & 1u)) >> 16);
}
// fast sigmoid/tanh on v_exp + v_rcp (exact limits at +-inf)
__device__ __forceinline__ float fsig(float x) {
  return __builtin_amdgcn_rcpf(1.f + __expf(-x));
}
__device__ __forceinline__ float ftanh(float x) {
  return 1.f - 2.f * __builtin_amdgcn_rcpf(__expf(2.f * x) + 1.f);
}

// ---------------- utility kernels ----------------
__global__ void k_zero_i32(int* __restrict__ p, int n) {
  for (int i = blockIdx.x * blockDim.x + threadIdx.x; i < n; i += gridDim.x * blockDim.x)
    p[i] = 0;
}
__global__ void k_zero_f32(float* __restrict__ p, int n) {
  for (int i = blockIdx.x * blockDim.x + threadIdx.x; i < n; i += gridDim.x * blockDim.x)
    p[i] = 0.f;
}
__global__ void k_hist(const int* __restrict__ dst, int* __restrict__ cnt, int nE) {
  int e = blockIdx.x * blockDim.x + threadIdx.x;
  if (e < nE) atomicAdd(&cnt[dst[e]], 1);
}

// ---- hierarchical scan: blk -> top -> fin (writes off+cursor)
__global__ __launch_bounds__(256) void k_scan_blk(const int* __restrict__ cnt,
                                                  int* __restrict__ incl,
                                                  int* __restrict__ bsum, int n) {
  __shared__ int buf[256];
  int i = blockIdx.x * 256 + threadIdx.x;
  int v = (i < n) ? cnt[i] : 0;
  buf[threadIdx.x] = v;
  __syncthreads();
#pragma unroll
  for (int d = 1; d < 256; d <<= 1) {
    int t = (threadIdx.x >= d) ? buf[threadIdx.x - d] : 0;
    __syncthreads();
    buf[threadIdx.x] += t;
    __syncthreads();
  }
  if (i < n) incl[i] = buf[threadIdx.x];
  if (threadIdx.x == 255) bsum[blockIdx.x] = buf[255];
}
__global__ __launch_bounds__(256) void k_scan_top(int* __restrict__ bsum, int nb) {
  __shared__ int buf[256];
  int v = (threadIdx.x < nb) ? bsum[threadIdx.x] : 0;
  buf[threadIdx.x] = v;
  __syncthreads();
#pragma unroll
  for (int d = 1; d < 256; d <<= 1) {
    int t = (threadIdx.x >= d) ? buf[threadIdx.x - d] : 0;
    __syncthreads();
    buf[threadIdx.x] += t;
    __syncthreads();
  }
  if (threadIdx.x < nb) bsum[threadIdx.x] = buf[threadIdx.x] - v;  // exclusive
}
__global__ __launch_bounds__(256) void k_scan_fin(const int* __restrict__ cnt,
                                                  const int* __restrict__ incl,
                                                  const int* __restrict__ bsum,
                                                  int* __restrict__ off,
                                                  int* __restrict__ cursor, int n) {
  int i = blockIdx.x * 256 + threadIdx.x;
  if (i < n) {
    int o = incl[i] + bsum[blockIdx.x];
    off[i + 1] = o;
    cursor[i] = o - cnt[i];
  }
  if (i == 0) off[0] = 0;
}

__global__ void k_scatter(const int* __restrict__ dst, const int* __restrict__ src,
                          int* __restrict__ cursor, int* __restrict__ slist, int nE) {
  int e = blockIdx.x * blockDim.x + threadIdx.x;
  if (e < nE) {
    int d = dst[e];
    int pos = atomicAdd(&cursor[d], 1);
    slist[pos] = src[e];
  }
}

// fp32 [NN][200] -> bf16 state rows, 512B-aligned stride ROWU
__global__ void k_pack_hi(const float* __restrict__ x, ushort* __restrict__ hHi, int nch) {
  for (int i = blockIdx.x * blockDim.x + threadIdx.x; i < nch;
       i += gridDim.x * blockDim.x) {
    int row = i / 25, j = i - row * 25;
    const float* s = x + (size_t)row * DIM + j * 8;
    uint w[4];
#pragma unroll
    for (int k = 0; k < 4; ++k)
      w[k] = (uint)bf16rn(s[k * 2]) | ((uint)bf16rn(s[k * 2 + 1]) << 16);
    *reinterpret_cast<uint4*>(hHi + (size_t)row * ROWU + j * 8) =
        make_uint4(w[0], w[1], w[2], w[3]);
  }
}

// elementwise fp32 -> bf16 ushort
__global__ void k_pack_bf(const float* __restrict__ in, ushort* __restrict__ out, int n) {
  for (int i = blockIdx.x * blockDim.x + threadIdx.x; i < n; i += gridDim.x * blockDim.x)
    out[i] = bf16rn(in[i]);
}

// bias staging buffer: bstg[(mat*200+c)*8] = bf16(bias), rest zero
__global__ void k_prep_bias(const float* __restrict__ b_ih, const float* __restrict__ b_hh,
                            ushort* __restrict__ bstg) {
  int idx = blockIdx.x * blockDim.x + threadIdx.x;
  if (idx < 6 * DIM) {
    int mat = idx / DIM, c = idx - mat * DIM;
    int g = mat >> 1;
    float v = (mat & 1) ? b_hh[g * DIM + c] : b_ih[g * DIM + c];
    ushort* d = bstg + (size_t)idx * 8;
    d[0] = bf16rn(v);
#pragma unroll
    for (int j = 1; j < 8; ++j) d[j] = 0;
  }
}

// ---------------- batched: wcB[s][c][k] = bf16( sum_m ggnn_w[s][k][m] * w_ih[c][m] )
#define GBM 64
#define GBN 64
#define GBK 8
__global__ __launch_bounds__(256) void k_gemm_wc(const float* __restrict__ gg,
                                                 const float* __restrict__ w_ih,
                                                 ushort* __restrict__ wcB) {
  __shared__ __align__(16) float As[GBK][GBM];
  __shared__ __align__(16) float Bs[GBK][GBN];
  int s = blockIdx.z;
  const float* A = gg + (size_t)s * DIM * DIM;   // [200][200] rows=k
  ushort* out = wcB + (size_t)s * 3 * DIM * DIM; // [600][200]
  int tid = threadIdx.x;
  int row0 = blockIdx.y * GBM;   // k
  int col0 = blockIdx.x * GBN;   // c
  int ty = tid >> 4, tx = tid & 15;
  float acc[4][4] = {};
  for (int k0 = 0; k0 < DIM; k0 += GBK) {
    {
      int r = tid >> 2;
      int kk = (tid & 3) * 2;
      int gr = row0 + r;
      float2 v = make_float2(0.f, 0.f);
      if (gr < DIM) v = *reinterpret_cast<const float2*>(&A[(size_t)gr * DIM + k0 + kk]);
      As[kk][r] = v.x; As[kk + 1][r] = v.y;
    }
    {
      int n = tid >> 2;
      int kk = (tid & 3) * 2;
      int gn = col0 + n;
      float2 v = *reinterpret_cast<const float2*>(&w_ih[(size_t)gn * DIM + k0 + kk]);
      Bs[kk][n] = v.x; Bs[kk + 1][n] = v.y;
    }
    __syncthreads();
#pragma unroll
    for (int k = 0; k < GBK; ++k) {
      float4 av = *reinterpret_cast<const float4*>(&As[k][ty * 4]);
      float4 bv = *reinterpret_cast<const float4*>(&Bs[k][tx * 4]);
      float a[4] = {av.x, av.y, av.z, av.w};
      float b[4] = {bv.x, bv.y, bv.z, bv.w};
#pragma unroll
      for (int i = 0; i < 4; ++i)
#pragma unroll
        for (int j = 0; j < 4; ++j) acc[i][j] += a[i] * b[j];
    }
    __syncthreads();
  }
#pragma unroll
  for (int i = 0; i < 4; ++i) {
    int r = row0 + ty * 4 + i;
    if (r >= DIM) continue;
#pragma unroll
    for (int j = 0; j < 4; ++j) {
      int c = col0 + tx * 4 + j;
      out[(size_t)c * DIM + r] = bf16rn(acc[i][j]);   // transposed store
    }
  }
}

// ---------------- aggregation: 2 nodes per wave (r18 form), aligned rows -------
__global__ __launch_bounds__(256) void k_aggregate_hi(const ushort* __restrict__ hHi,
                                                      const int* __restrict__ off,
                                                      const int* __restrict__ slist,
                                                      ushort* __restrict__ aggHi) {
  int wid = blockIdx.x * 4 + (threadIdx.x >> 6);
  int half = (threadIdx.x >> 5) & 1;
  int node = wid * 2 + half;
  int lane32 = threadIdx.x & 31;
  bool nok = node < NN;
  bool act = (lane32 < 25) && nok;
  const uint4* hb = reinterpret_cast<const uint4*>(hHi);
  float a[8] = {};
  int beg = 0, end = 0;
  if (nok) { beg = off[node]; end = off[node + 1]; }
  int p = beg;
#define ACC8(q)                                                   \
  {                                                               \
    a[0] += __uint_as_float((q).x << 16);                         \
    a[1] += __uint_as_float((q).x & 0xffff0000u);                 \
    a[2] += __uint_as_float((q).y << 16);                         \
    a[3] += __uint_as_float((q).y & 0xffff0000u);                 \
    a[4] += __uint_as_float((q).z << 16);                         \
    a[5] += __uint_as_float((q).z & 0xffff0000u);                 \
    a[6] += __uint_as_float((q).w << 16);                         \
    a[7] += __uint_as_float((q).w & 0xffff0000u);                 \
  }
  for (; p + 7 < end; p += 8) {
    uint4 q[8];
    if (act) {
#pragma unroll
      for (int e = 0; e < 8; ++e) q[e] = hb[(size_t)slist[p + e] * ROWQ + lane32];
#pragma unroll
      for (int e = 0; e < 8; ++e) ACC8(q[e])
    }
  }
  for (; p + 3 < end; p += 4) {
    uint4 q[4];
    if (act) {
#pragma unroll
      for (int e = 0; e < 4; ++e) q[e] = hb[(size_t)slist[p + e] * ROWQ + lane32];
#pragma unroll
      for (int e = 0; e < 4; ++e) ACC8(q[e])
    }
  }
  for (; p < end; ++p) {
    int s = slist[p];
    if (act) {
      uint4 q = hb[(size_t)s * ROWQ + lane32];
      ACC8(q)
    }
  }
#undef ACC8
  if (act) {
    uint w[4];
#pragma unroll
    for (int j = 0; j < 4; ++j)
      w[j] = (uint)bf16rn(a[j * 2]) | ((uint)bf16rn(a[j * 2 + 1]) << 16);
    reinterpret_cast<uint4*>(aggHi)[(size_t)node * ROWQ + lane32] =
        make_uint4(w[0], w[1], w[2], w[3]);
  }
}

// ---------------- fused MFMA GRU step (bf16-only state, aligned rows) ----------
// bf16 operands AND bf16 state. Bias folded into MFMA via B-chunk 25 + A=1
// slice. Block: 256 thr (4 waves), 32 rows/wave, 32-col slice. B resident in
// LDS (78 KB -> 2 blocks/CU); A direct 16B loads, ring-4 prefetch.
#define NPAN 391            // ceil(NN/128)
#define PPC 3
#define NCHK 131            // 131*3 = 393 >= 391
#define NCOLB 7
#define GRIDF 917           // 7*131; swizzle q=114 r=5

#define MFMA16(a, b, c) __builtin_amdgcn_mfma_f32_16x16x32_bf16(a, b, c, 0, 0, 0)

__global__ __launch_bounds__(256, 2) void k_fused_mfma(
    const ushort* __restrict__ aggHi, const ushort* __restrict__ hHi,
    const ushort* __restrict__ wcB, const ushort* __restrict__ whB,
    const ushort* __restrict__ bstg,
    ushort* __restrict__ hnHi) {
  __shared__ uint4 Bb[6][26][32];   // 79872 B -> 2 blocks/CU

  int tid = threadIdx.x;
  int lane = tid & 63;
  int wv = tid >> 6;          // 0..3
  int lr = lane & 15;
  int kc = lane >> 4;         // 0..3

  // XCD-aware bijective swizzle (m204): nwg=917, q=114, r=5
  int x = blockIdx.x & 7, ii = blockIdx.x >> 3;
  int work = (x < 5 ? x * 115 : 575 + (x - 5) * 114) + ii;
  int chunk = work / NCOLB;
  int col = work - chunk * NCOLB;
  int cc0 = col * 32;

  int c0 = cc0 + lr;
  int c1 = c0 + 16;
  bool c0ok = c0 < DIM, c1ok = c1 < DIM;
  int c0c = c0ok ? c0 : DIM - 1;
  int c1c = c1ok ? c1 : DIM - 1;

  // ---- stage B once: 6 mats x 26 ch x 32 cols = 4992 uint4 (ch 25 = biases) ----
  {
    uint4* BbF = &Bb[0][0][0];
    for (int i2 = 0; i2 < 20; ++i2) {
      int u = tid + i2 * 256;
      if (u < 4992) {
        int mat = u / 832;
        int rem = u - mat * 832;
        int ch = rem >> 5;
        int c = rem & 31;
        int gc = cc0 + c; if (gc > 199) gc = 199;
        if (ch < 25) {
          const ushort* wsrc = (mat & 1) ? whB : wcB;
          GLL16(wsrc + (size_t)(((mat >> 1) * DIM) + gc) * DIM + ch * 8, BbF + u);
        } else {
          GLL16(bstg + (size_t)(mat * DIM + gc) * 8, BbF + u);
        }
      }
    }
  }
  __syncthreads();   // the ONLY block-wide barrier

  for (int j = 0; j < PPC; ++j) {
    int p = chunk * PPC + j;
    if (p >= NPAN) break;
    int prow0 = p * 128;
    int r0 = prow0 + wv * 32 + lr;
    int r1 = r0 + 16;
    int rc0 = r0 < NN ? r0 : NN - 1;
    int rc1 = r1 < NN ? r1 : NN - 1;
    const ushort* a0 = aggHi + (size_t)rc0 * ROWU;
    const ushort* a1 = aggHi + (size_t)rc1 * ROWU;
    const ushort* h0 = hHi + (size_t)rc0 * ROWU;
    const ushort* h1 = hHi + (size_t)rc1 * ROWU;

    // hoisted per-panel output row bases, reused by hv-prefetch + stores
    uint rbase[2][4];
    bool rok[2][4];
#pragma unroll
    for (int rf = 0; rf < 2; ++rf)
#pragma unroll
      for (int qq = 0; qq < 4; ++qq) {
        int r_ = prow0 + wv * 32 + rf * 16 + kc * 4 + qq;
        rok[rf][qq] = r_ < NN;
        rbase[rf][qq] = (uint)(r_ < NN ? r_ : NN - 1) * ROWU;
      }

    f32x4 acc[3][2][2][2] = {};   // [gate][mat 0=agg,1=h][rf][ct]
    short8 aq[4][2][2];           // [ring4][mat][rf]
    ushort hvh[2][2][4];          // prefetched bf16 h-state for epilogue

#define LDA(d, t)                                                              \
  {                                                                            \
    if ((t) < 6) {                                                             \
      const int of_ = (t) * 32 + kc * 8;                                       \
      aq[d][0][0] = *reinterpret_cast<const short8*>(a0 + of_);                \
      aq[d][0][1] = *reinterpret_cast<const short8*>(a1 + of_);                \
      aq[d][1][0] = *reinterpret_cast<const short8*>(h0 + of_);                \
      aq[d][1][1] = *reinterpret_cast<const short8*>(h1 + of_);                \
    } else if (kc == 0) {                                                      \
      aq[d][0][0] = *reinterpret_cast<const short8*>(a0 + 192);                \
      aq[d][0][1] = *reinterpret_cast<const short8*>(a1 + 192);                \
      aq[d][1][0] = *reinterpret_cast<const short8*>(h0 + 192);                \
      aq[d][1][1] = *reinterpret_cast<const short8*>(h1 + 192);                \
    } else {                                                                   \
      const short8 z_ = {0, 0, 0, 0, 0, 0, 0, 0};                              \
      const short8 o_ = {(short)0x3F80, 0, 0, 0, 0, 0, 0, 0};                  \
      short8 v_ = (kc == 1) ? o_ : z_;                                         \
      aq[d][0][0] = v_; aq[d][0][1] = v_;                                      \
      aq[d][1][0] = v_; aq[d][1][1] = v_;                                      \
    }                                                                          \
  }

    LDA(0, 0)
    LDA(1, 1)
    LDA(2, 2)
#pragma unroll
    for (int t = 0; t < 7; ++t) {
      const int cur = t & 3;
      if (t < 4) LDA((t + 3) & 3, t + 3)
      if (t == 5) {
        // prefetch epilogue state under the last ktiles' MFMA
#pragma unroll
        for (int rf = 0; rf < 2; ++rf)
#pragma unroll
          for (int qq = 0; qq < 4; ++qq) {
            hvh[0][rf][qq] = hHi[rbase[rf][qq] + c0c];
            hvh[1][rf][qq] = hHi[rbase[rf][qq] + c1c];
          }
      }
      int bch = t * 4 + kc; if (bch >= 26) bch = 24;   // t=6: kc0->24, kc1->25(bias)
      __builtin_amdgcn_s_setprio(1);
#pragma unroll
      for (int g = 0; g < 3; ++g) {
#pragma unroll
        for (int ct = 0; ct < 2; ++ct) {
          short8 b1 = *reinterpret_cast<const short8*>(&Bb[g * 2 + 0][bch][ct * 16 + lr]);
          short8 b2 = *reinterpret_cast<const short8*>(&Bb[g * 2 + 1][bch][ct * 16 + lr]);
#pragma unroll
          for (int rf = 0; rf < 2; ++rf) {
            acc[g][0][rf][ct] = MFMA16(aq[cur][0][rf], b1, acc[g][0][rf][ct]);
            acc[g][1][rf][ct] = MFMA16(aq[cur][1][rf], b2, acc[g][1][rf][ct]);
          }
        }
      }
      __builtin_amdgcn_s_setprio(0);
    }
#undef LDA

    // ---- epilogue: GRU gates (biases already in acc), bf16 state store ----
#pragma unroll
    for (int ct = 0; ct < 2; ++ct) {
      if (!(ct ? c1ok : c0ok)) continue;
      int cc = ct ? c1 : c0;
#pragma unroll
      for (int rf = 0; rf < 2; ++rf) {
#pragma unroll
        for (int qq = 0; qq < 4; ++qq) {
          if (!rok[rf][qq]) continue;
          uint base = rbase[rf][qq] + cc;
          float gir = acc[0][0][rf][ct][qq];
          float giz = acc[1][0][rf][ct][qq];
          float gin = acc[2][0][rf][ct][qq];
          float ghr = acc[0][1][rf][ct][qq];
          float ghz = acc[1][1][rf][ct][qq];
          float ghn = acc[2][1][rf][ct][qq];
          float rr = fsig(gir + ghr);
          float zz = fsig(giz + ghz);
          float nn = ftanh(gin + rr * ghn);
          float hv = bfu(hvh[ct][rf][qq]);
          float v = fmaf(zz, hv - nn, nn);
          hnHi[base] = bf16rn(v);
        }
      }
    }
  }
}

// ---------------- relu + segment_max pooling (bf16 state) ----------------
__global__ __launch_bounds__(256) void k_pool(const ushort* __restrict__ hHi,
                                              const int* __restrict__ batch,
                                              float* __restrict__ pooled) {
  int i = blockIdx.x;
  int j = threadIdx.x;
  if (j < DIM) {
    int g = batch[i];
    float v = bfu(hHi[(size_t)i * ROWU + j]);
    v = v > 0.f ? v : 0.f;
    atomicMax((int*)&pooled[(size_t)g * DIM + j], __float_as_int(v));
  }
}

__global__ __launch_bounds__(256) void k_classify(const float* __restrict__ pooled,
                                                  const float* __restrict__ w,
                                                  const float* __restrict__ b,
                                                  float* __restrict__ out) {
  __shared__ float r0[256], r1[256];
  int g = blockIdx.x;
  int j = threadIdx.x;
  float p = (j < DIM) ? pooled[(size_t)g * DIM + j] : 0.f;
  r0[j] = (j < DIM) ? p * w[j] : 0.f;
  r1[j] = (j < DIM) ? p * w[DIM + j] : 0.f;
  __syncthreads();
  for (int d = 128; d > 0; d >>= 1) {
    if (j < d) { r0[j] += r0[j + d]; r1[j] += r1[j + d]; }
    __syncthreads();
  }
  if (j == 0) {
    out[g * 2 + 0] = 1.f / (1.f + expf(-(r0[0] + b[0])));
    out[g * 2 + 1] = 1.f / (1.f + expf(-(r1[0] + b[1])));
  }
}

// ---------------- host ----------------
extern "C" void kernel_launch(void* const* d_in, const int* in_sizes, int n_in,
                              void* d_out, int out_size, void* d_ws, size_t ws_size,
                              hipStream_t stream) {
  const float* x = (const float*)d_in[0];
  const int* edge_index = (const int*)d_in[1];
  const int* batch = (const int*)d_in[2];
  const float* ggnn_w = (const float*)d_in[3];
  const float* w_ih = (const float*)d_in[4];
  const float* w_hh = (const float*)d_in[5];
  const float* b_ih = (const float*)d_in[6];
  const float* b_hh = (const float*)d_in[7];
  const float* cls_w = (const float*)d_in[8];
  const float* cls_b = (const float*)d_in[9];
  float* out = (float*)d_out;

  const int* src = edge_index;       // edge_index[0]
  const int* dst = edge_index + NE;  // edge_index[1]

  char* wsb = (char*)d_ws;
  size_t off = 0;
  auto alloc = [&](size_t bytes) -> void* {
    void* p = wsb + off;
    off += (bytes + 255) & ~(size_t)255;
    return p;
  };
  ushort* hHiA = (ushort*)alloc((size_t)NN * ROWU * 2);   // 25.6 MB
  ushort* hHiB = (ushort*)alloc((size_t)NN * ROWU * 2);   // 25.6 MB
  ushort* aggHi = (ushort*)alloc((size_t)NN * ROWU * 2);  // 25.6 MB
  ushort* wcB = (ushort*)alloc((size_t)NSTEPS * 3 * DIM * DIM * 2);  // 1.44 MB
  ushort* whB = (ushort*)alloc((size_t)3 * DIM * DIM * 2);           // 240 KB
  ushort* bstg = (ushort*)alloc((size_t)6 * DIM * 8 * 2);            // 19.2 KB
  float* pooled = (float*)alloc((size_t)NG * DIM * 4);
  int* indeg = (int*)alloc((size_t)NN * 4);
  int* offs = (int*)alloc((size_t)(NN + 1) * 4);
  int* incl = (int*)alloc((size_t)NN * 4);
  int* bsum = (int*)alloc((size_t)256 * 4);
  int* cursor = (int*)alloc((size_t)NN * 4);
  int* slist = (int*)alloc((size_t)NE * 4);
  if (off > ws_size) return;  // fail loud (absmax) instead of faulting

  const int NB = (NN + 255) / 256;   // 196

  // h0 = bf16(x) into aligned rows
  k_pack_hi<<<2048, 256, 0, stream>>>(x, hHiA, NN * 25);

  // CSR build (dst -> src list)
  k_zero_i32<<<196, 256, 0, stream>>>(indeg, NN);
  k_hist<<<(NE + 255) / 256, 256, 0, stream>>>(dst, indeg, NE);
  k_scan_blk<<<NB, 256, 0, stream>>>(indeg, incl, bsum, NN);
  k_scan_top<<<1, 256, 0, stream>>>(bsum, NB);
  k_scan_fin<<<NB, 256, 0, stream>>>(indeg, incl, bsum, offs, cursor, NN);
  k_scatter<<<(NE + 255) / 256, 256, 0, stream>>>(dst, src, cursor, slist, NE);

  // weights + biases
  {
    dim3 g((3 * DIM + GBN - 1) / GBN, (DIM + GBM - 1) / GBM, NSTEPS);
    k_gemm_wc<<<g, 256, 0, stream>>>(ggnn_w, w_ih, wcB);
    k_pack_bf<<<512, 256, 0, stream>>>(w_hh, whB, 3 * DIM * DIM);
    k_prep_bias<<<5, 256, 0, stream>>>(b_ih, b_hh, bstg);
  }

  k_zero_f32<<<200, 256, 0, stream>>>(pooled, NG * DIM);

  ushort* hHic = hHiA;
  ushort* hHin = hHiB;
  for (int s = 0; s < NSTEPS; ++s) {
    k_aggregate_hi<<<(NN / 2 + 3) / 4, 256, 0, stream>>>(hHic, offs, slist, aggHi);
    k_fused_mfma<<<GRIDF, 256, 0, stream>>>(aggHi, hHic,
                                            wcB + (size_t)s * 3 * DIM * DIM,
                                            whB, bstg, hHin);
    ushort* t = hHic; hHic = hHin; hHin = t;
  }

  k_pool<<<NN, 256, 0, stream>>>(hHic, batch, pooled);
  k_classify<<<NG, 256, 0, stream>>>(pooled, cls_w, cls_b, out);
}

// Round 21
// 600.831 us; speedup vs baseline: 1.1100x; 1.1100x over previous
//
#include <hip/hip_runtime.h>
#include <cstdint>
#include <cstddef>

#define NN 50000
#define NE 400000
#define NG 256
#define DIM 200
#define NSTEPS 6

typedef unsigned int uint;
typedef unsigned short ushort;
typedef __attribute__((ext_vector_type(8))) short short8;
typedef __attribute__((ext_vector_type(4))) float f32x4;

#define GLL16(gsrc, ldst)                                                        \
  __builtin_amdgcn_global_load_lds(                                              \
      (const __attribute__((address_space(1))) void*)(gsrc),                     \
      (__attribute__((address_space(3))) void*)(ldst), 16, 0, 0)

__device__ __forceinline__ float bfu(ushort u) { return __uint_as_float((uint)u << 16); }
__device__ __forceinline__ ushort bf16rn(float v) {
  uint u = __float_as_uint(v);
  return (ushort)((u + 0x7fffu + ((u >> 16) & 1u)) >> 16);
}
// fast sigmoid/tanh on v_exp + v_rcp (exact limits at +-inf)
__device__ __forceinline__ float fsig(float x) {
  return __builtin_amdgcn_rcpf(1.f + __expf(-x));
}
__device__ __forceinline__ float ftanh(float x) {
  return 1.f - 2.f * __builtin_amdgcn_rcpf(__expf(2.f * x) + 1.f);
}

// ---------------- utility kernels ----------------
__global__ void k_zero_i32(int* __restrict__ p, int n) {
  for (int i = blockIdx.x * blockDim.x + threadIdx.x; i < n; i += gridDim.x * blockDim.x)
    p[i] = 0;
}
__global__ void k_zero_f32(float* __restrict__ p, int n) {
  for (int i = blockIdx.x * blockDim.x + threadIdx.x; i < n; i += gridDim.x * blockDim.x)
    p[i] = 0.f;
}
__global__ void k_hist(const int* __restrict__ dst, int* __restrict__ cnt, int nE) {
  int e = blockIdx.x * blockDim.x + threadIdx.x;
  if (e < nE) atomicAdd(&cnt[dst[e]], 1);
}

// ---- hierarchical scan: blk -> top -> fin (writes off+cursor)
__global__ __launch_bounds__(256) void k_scan_blk(const int* __restrict__ cnt,
                                                  int* __restrict__ incl,
                                                  int* __restrict__ bsum, int n) {
  __shared__ int buf[256];
  int i = blockIdx.x * 256 + threadIdx.x;
  int v = (i < n) ? cnt[i] : 0;
  buf[threadIdx.x] = v;
  __syncthreads();
#pragma unroll
  for (int d = 1; d < 256; d <<= 1) {
    int t = (threadIdx.x >= d) ? buf[threadIdx.x - d] : 0;
    __syncthreads();
    buf[threadIdx.x] += t;
    __syncthreads();
  }
  if (i < n) incl[i] = buf[threadIdx.x];
  if (threadIdx.x == 255) bsum[blockIdx.x] = buf[255];
}
__global__ __launch_bounds__(256) void k_scan_top(int* __restrict__ bsum, int nb) {
  __shared__ int buf[256];
  int v = (threadIdx.x < nb) ? bsum[threadIdx.x] : 0;
  buf[threadIdx.x] = v;
  __syncthreads();
#pragma unroll
  for (int d = 1; d < 256; d <<= 1) {
    int t = (threadIdx.x >= d) ? buf[threadIdx.x - d] : 0;
    __syncthreads();
    buf[threadIdx.x] += t;
    __syncthreads();
  }
  if (threadIdx.x < nb) bsum[threadIdx.x] = buf[threadIdx.x] - v;  // exclusive
}
__global__ __launch_bounds__(256) void k_scan_fin(const int* __restrict__ cnt,
                                                  const int* __restrict__ incl,
                                                  const int* __restrict__ bsum,
                                                  int* __restrict__ off,
                                                  int* __restrict__ cursor, int n) {
  int i = blockIdx.x * 256 + threadIdx.x;
  if (i < n) {
    int o = incl[i] + bsum[blockIdx.x];
    off[i + 1] = o;
    cursor[i] = o - cnt[i];
  }
  if (i == 0) off[0] = 0;
}

__global__ void k_scatter(const int* __restrict__ dst, const int* __restrict__ src,
                          int* __restrict__ cursor, int* __restrict__ slist, int nE) {
  int e = blockIdx.x * blockDim.x + threadIdx.x;
  if (e < nE) {
    int d = dst[e];
    int pos = atomicAdd(&cursor[d], 1);
    slist[pos] = src[e];
  }
}

// fp32 -> bf16 operand/state array
__global__ void k_pack_hi(const float* __restrict__ x, ushort* __restrict__ hHi, int n8) {
  for (int i = blockIdx.x * blockDim.x + threadIdx.x; i < n8;
       i += gridDim.x * blockDim.x) {
    const float* s = x + (size_t)i * 8;
    uint w[4];
#pragma unroll
    for (int j = 0; j < 4; ++j)
      w[j] = (uint)bf16rn(s[j * 2]) | ((uint)bf16rn(s[j * 2 + 1]) << 16);
    *reinterpret_cast<uint4*>(hHi + (size_t)i * 8) = make_uint4(w[0], w[1], w[2], w[3]);
  }
}

// elementwise fp32 -> bf16 ushort
__global__ void k_pack_bf(const float* __restrict__ in, ushort* __restrict__ out, int n) {
  for (int i = blockIdx.x * blockDim.x + threadIdx.x; i < n; i += gridDim.x * blockDim.x)
    out[i] = bf16rn(in[i]);
}

// bias staging buffer: bstg[(mat*200+c)*8] = bf16(bias), rest zero
__global__ void k_prep_bias(const float* __restrict__ b_ih, const float* __restrict__ b_hh,
                            ushort* __restrict__ bstg) {
  int idx = blockIdx.x * blockDim.x + threadIdx.x;
  if (idx < 6 * DIM) {
    int mat = idx / DIM, c = idx - mat * DIM;
    int g = mat >> 1;
    float v = (mat & 1) ? b_hh[g * DIM + c] : b_ih[g * DIM + c];
    ushort* d = bstg + (size_t)idx * 8;
    d[0] = bf16rn(v);
#pragma unroll
    for (int j = 1; j < 8; ++j) d[j] = 0;
  }
}

// ---------------- batched: wcB[s][c][k] = bf16( sum_m ggnn_w[s][k][m] * w_ih[c][m] )
#define GBM 64
#define GBN 64
#define GBK 8
__global__ __launch_bounds__(256) void k_gemm_wc(const float* __restrict__ gg,
                                                 const float* __restrict__ w_ih,
                                                 ushort* __restrict__ wcB) {
  __shared__ __align__(16) float As[GBK][GBM];
  __shared__ __align__(16) float Bs[GBK][GBN];
  int s = blockIdx.z;
  const float* A = gg + (size_t)s * DIM * DIM;   // [200][200] rows=k
  ushort* out = wcB + (size_t)s * 3 * DIM * DIM; // [600][200]
  int tid = threadIdx.x;
  int row0 = blockIdx.y * GBM;   // k
  int col0 = blockIdx.x * GBN;   // c
  int ty = tid >> 4, tx = tid & 15;
  float acc[4][4] = {};
  for (int k0 = 0; k0 < DIM; k0 += GBK) {
    {
      int r = tid >> 2;
      int kk = (tid & 3) * 2;
      int gr = row0 + r;
      float2 v = make_float2(0.f, 0.f);
      if (gr < DIM) v = *reinterpret_cast<const float2*>(&A[(size_t)gr * DIM + k0 + kk]);
      As[kk][r] = v.x; As[kk + 1][r] = v.y;
    }
    {
      int n = tid >> 2;
      int kk = (tid & 3) * 2;
      int gn = col0 + n;
      float2 v = *reinterpret_cast<const float2*>(&w_ih[(size_t)gn * DIM + k0 + kk]);
      Bs[kk][n] = v.x; Bs[kk + 1][n] = v.y;
    }
    __syncthreads();
#pragma unroll
    for (int k = 0; k < GBK; ++k) {
      float4 av = *reinterpret_cast<const float4*>(&As[k][ty * 4]);
      float4 bv = *reinterpret_cast<const float4*>(&Bs[k][tx * 4]);
      float a[4] = {av.x, av.y, av.z, av.w};
      float b[4] = {bv.x, bv.y, bv.z, bv.w};
#pragma unroll
      for (int i = 0; i < 4; ++i)
#pragma unroll
        for (int j = 0; j < 4; ++j) acc[i][j] += a[i] * b[j];
    }
    __syncthreads();
  }
#pragma unroll
  for (int i = 0; i < 4; ++i) {
    int r = row0 + ty * 4 + i;
    if (r >= DIM) continue;
#pragma unroll
    for (int j = 0; j < 4; ++j) {
      int c = col0 + tx * 4 + j;
      out[(size_t)c * DIM + r] = bf16rn(acc[i][j]);   // transposed store
    }
  }
}

// ---------------- aggregation: 2 nodes per wave, 8-deep gather MLP ----------------
__global__ __launch_bounds__(256) void k_aggregate_hi(const ushort* __restrict__ hHi,
                                                      const int* __restrict__ off,
                                                      const int* __restrict__ slist,
                                                      ushort* __restrict__ aggHi) {
  int wid = blockIdx.x * 4 + (threadIdx.x >> 6);
  int half = (threadIdx.x >> 5) & 1;
  int node = wid * 2 + half;
  int lane32 = threadIdx.x & 31;
  bool nok = node < NN;
  bool act = (lane32 < 25) && nok;
  const uint4* hb = reinterpret_cast<const uint4*>(hHi);
  float a[8] = {};
  int beg = 0, end = 0;
  if (nok) { beg = off[node]; end = off[node + 1]; }
  int p = beg;
#define ACC8(q)                                                   \
  {                                                               \
    a[0] += __uint_as_float((q).x << 16);                         \
    a[1] += __uint_as_float((q).x & 0xffff0000u);                 \
    a[2] += __uint_as_float((q).y << 16);                         \
    a[3] += __uint_as_float((q).y & 0xffff0000u);                 \
    a[4] += __uint_as_float((q).z << 16);                         \
    a[5] += __uint_as_float((q).z & 0xffff0000u);                 \
    a[6] += __uint_as_float((q).w << 16);                         \
    a[7] += __uint_as_float((q).w & 0xffff0000u);                 \
  }
  for (; p + 7 < end; p += 8) {
    uint4 q[8];
    if (act) {
#pragma unroll
      for (int e = 0; e < 8; ++e) q[e] = hb[(size_t)slist[p + e] * 25 + lane32];
#pragma unroll
      for (int e = 0; e < 8; ++e) ACC8(q[e])
    }
  }
  for (; p + 3 < end; p += 4) {
    uint4 q[4];
    if (act) {
#pragma unroll
      for (int e = 0; e < 4; ++e) q[e] = hb[(size_t)slist[p + e] * 25 + lane32];
#pragma unroll
      for (int e = 0; e < 4; ++e) ACC8(q[e])
    }
  }
  for (; p < end; ++p) {
    int s = slist[p];
    if (act) {
      uint4 q = hb[(size_t)s * 25 + lane32];
      ACC8(q)
    }
  }
#undef ACC8
  if (act) {
    uint w[4];
#pragma unroll
    for (int j = 0; j < 4; ++j)
      w[j] = (uint)bf16rn(a[j * 2]) | ((uint)bf16rn(a[j * 2 + 1]) << 16);
    reinterpret_cast<uint4*>(aggHi)[(size_t)node * 25 + lane32] =
        make_uint4(w[0], w[1], w[2], w[3]);
  }
}

// ---------------- fused MFMA GRU step (bf16-only state) ----------
// bf16 operands AND bf16 state. Bias folded into MFMA via B-chunk 25 + A=1
// slice. Block: 256 thr (4 waves), 32 rows/wave, 32-col slice. B resident in
// LDS (78 KB -> 2 blocks/CU); A direct 16B loads, ring-4 prefetch.
#define NPAN 391            // ceil(NN/128)
#define PPC 3
#define NCHK 131            // 131*3 = 393 >= 391
#define NCOLB 7
#define GRIDF 917           // 7*131; swizzle q=114 r=5

#define MFMA16(a, b, c) __builtin_amdgcn_mfma_f32_16x16x32_bf16(a, b, c, 0, 0, 0)

__global__ __launch_bounds__(256, 2) void k_fused_mfma(
    const ushort* __restrict__ aggHi, const ushort* __restrict__ hHi,
    const ushort* __restrict__ wcB, const ushort* __restrict__ whB,
    const ushort* __restrict__ bstg,
    ushort* __restrict__ hnHi) {
  __shared__ uint4 Bb[6][26][32];   // 79872 B -> 2 blocks/CU

  int tid = threadIdx.x;
  int lane = tid & 63;
  int wv = tid >> 6;          // 0..3
  int lr = lane & 15;
  int kc = lane >> 4;         // 0..3

  // XCD-aware bijective swizzle (m204): nwg=917, q=114, r=5
  int x = blockIdx.x & 7, ii = blockIdx.x >> 3;
  int work = (x < 5 ? x * 115 : 575 + (x - 5) * 114) + ii;
  int chunk = work / NCOLB;
  int col = work - chunk * NCOLB;
  int cc0 = col * 32;

  int c0 = cc0 + lr;
  int c1 = c0 + 16;
  bool c0ok = c0 < DIM, c1ok = c1 < DIM;
  int c0c = c0ok ? c0 : DIM - 1;
  int c1c = c1ok ? c1 : DIM - 1;

  // ---- stage B once: 6 mats x 26 ch x 32 cols = 4992 uint4 (ch 25 = biases) ----
  {
    uint4* BbF = &Bb[0][0][0];
    for (int i2 = 0; i2 < 20; ++i2) {
      int u = tid + i2 * 256;
      if (u < 4992) {
        int mat = u / 832;
        int rem = u - mat * 832;
        int ch = rem >> 5;
        int c = rem & 31;
        int gc = cc0 + c; if (gc > 199) gc = 199;
        if (ch < 25) {
          const ushort* wsrc = (mat & 1) ? whB : wcB;
          GLL16(wsrc + (size_t)(((mat >> 1) * DIM) + gc) * DIM + ch * 8, BbF + u);
        } else {
          GLL16(bstg + (size_t)(mat * DIM + gc) * 8, BbF + u);
        }
      }
    }
  }
  __syncthreads();   // the ONLY block-wide barrier

  for (int j = 0; j < PPC; ++j) {
    int p = chunk * PPC + j;
    if (p >= NPAN) break;
    int prow0 = p * 128;
    int r0 = prow0 + wv * 32 + lr;
    int r1 = r0 + 16;
    int rc0 = r0 < NN ? r0 : NN - 1;
    int rc1 = r1 < NN ? r1 : NN - 1;
    const ushort* a0 = aggHi + (size_t)rc0 * DIM;
    const ushort* a1 = aggHi + (size_t)rc1 * DIM;
    const ushort* h0 = hHi + (size_t)rc0 * DIM;
    const ushort* h1 = hHi + (size_t)rc1 * DIM;

    // hoisted per-panel output row bases, reused by hv-prefetch + stores
    uint rbase[2][4];
    bool rok[2][4];
#pragma unroll
    for (int rf = 0; rf < 2; ++rf)
#pragma unroll
      for (int qq = 0; qq < 4; ++qq) {
        int r_ = prow0 + wv * 32 + rf * 16 + kc * 4 + qq;
        rok[rf][qq] = r_ < NN;
        rbase[rf][qq] = (uint)(r_ < NN ? r_ : NN - 1) * DIM;
      }

    f32x4 acc[3][2][2][2] = {};   // [gate][mat 0=agg,1=h][rf][ct]
    short8 aq[4][2][2];           // [ring4][mat][rf]
    ushort hvh[2][2][4];          // prefetched bf16 h-state for epilogue

#define LDA(d, t)                                                              \
  {                                                                            \
    if ((t) < 6) {                                                             \
      const int of_ = (t) * 32 + kc * 8;                                       \
      aq[d][0][0] = *reinterpret_cast<const short8*>(a0 + of_);                \
      aq[d][0][1] = *reinterpret_cast<const short8*>(a1 + of_);                \
      aq[d][1][0] = *reinterpret_cast<const short8*>(h0 + of_);                \
      aq[d][1][1] = *reinterpret_cast<const short8*>(h1 + of_);                \
    } else if (kc == 0) {                                                      \
      aq[d][0][0] = *reinterpret_cast<const short8*>(a0 + 192);                \
      aq[d][0][1] = *reinterpret_cast<const short8*>(a1 + 192);                \
      aq[d][1][0] = *reinterpret_cast<const short8*>(h0 + 192);                \
      aq[d][1][1] = *reinterpret_cast<const short8*>(h1 + 192);                \
    } else {                                                                   \
      const short8 z_ = {0, 0, 0, 0, 0, 0, 0, 0};                              \
      const short8 o_ = {(short)0x3F80, 0, 0, 0, 0, 0, 0, 0};                  \
      short8 v_ = (kc == 1) ? o_ : z_;                                         \
      aq[d][0][0] = v_; aq[d][0][1] = v_;                                      \
      aq[d][1][0] = v_; aq[d][1][1] = v_;                                      \
    }                                                                          \
  }

    LDA(0, 0)
    LDA(1, 1)
    LDA(2, 2)
#pragma unroll
    for (int t = 0; t < 7; ++t) {
      const int cur = t & 3;
      if (t < 4) LDA((t + 3) & 3, t + 3)
      if (t == 5) {
        // prefetch epilogue state under the last ktiles' MFMA
#pragma unroll
        for (int rf = 0; rf < 2; ++rf)
#pragma unroll
          for (int qq = 0; qq < 4; ++qq) {
            hvh[0][rf][qq] = hHi[rbase[rf][qq] + c0c];
            hvh[1][rf][qq] = hHi[rbase[rf][qq] + c1c];
          }
      }
      int bch = t * 4 + kc; if (bch >= 26) bch = 24;   // t=6: kc0->24, kc1->25(bias)
      __builtin_amdgcn_s_setprio(1);
#pragma unroll
      for (int g = 0; g < 3; ++g) {
#pragma unroll
        for (int ct = 0; ct < 2; ++ct) {
          short8 b1 = *reinterpret_cast<const short8*>(&Bb[g * 2 + 0][bch][ct * 16 + lr]);
          short8 b2 = *reinterpret_cast<const short8*>(&Bb[g * 2 + 1][bch][ct * 16 + lr]);
#pragma unroll
          for (int rf = 0; rf < 2; ++rf) {
            acc[g][0][rf][ct] = MFMA16(aq[cur][0][rf], b1, acc[g][0][rf][ct]);
            acc[g][1][rf][ct] = MFMA16(aq[cur][1][rf], b2, acc[g][1][rf][ct]);
          }
        }
      }
      __builtin_amdgcn_s_setprio(0);
    }
#undef LDA

    // ---- epilogue: GRU gates (biases already in acc), bf16 state store ----
#pragma unroll
    for (int ct = 0; ct < 2; ++ct) {
      if (!(ct ? c1ok : c0ok)) continue;
      int cc = ct ? c1 : c0;
#pragma unroll
      for (int rf = 0; rf < 2; ++rf) {
#pragma unroll
        for (int qq = 0; qq < 4; ++qq) {
          if (!rok[rf][qq]) continue;
          uint base = rbase[rf][qq] + cc;
          float gir = acc[0][0][rf][ct][qq];
          float giz = acc[1][0][rf][ct][qq];
          float gin = acc[2][0][rf][ct][qq];
          float ghr = acc[0][1][rf][ct][qq];
          float ghz = acc[1][1][rf][ct][qq];
          float ghn = acc[2][1][rf][ct][qq];
          float rr = fsig(gir + ghr);
          float zz = fsig(giz + ghz);
          float nn = ftanh(gin + rr * ghn);
          float hv = bfu(hvh[ct][rf][qq]);
          float v = fmaf(zz, hv - nn, nn);
          hnHi[base] = bf16rn(v);
        }
      }
    }
  }
}

// ---------------- relu + segment_max pooling (bf16 state) ----------------
__global__ __launch_bounds__(256) void k_pool(const ushort* __restrict__ hHi,
                                              const int* __restrict__ batch,
                                              float* __restrict__ pooled) {
  int i = blockIdx.x;
  int j = threadIdx.x;
  if (j < DIM) {
    int g = batch[i];
    float v = bfu(hHi[(size_t)i * DIM + j]);
    v = v > 0.f ? v : 0.f;
    atomicMax((int*)&pooled[(size_t)g * DIM + j], __float_as_int(v));
  }
}

__global__ __launch_bounds__(256) void k_classify(const float* __restrict__ pooled,
                                                  const float* __restrict__ w,
                                                  const float* __restrict__ b,
                                                  float* __restrict__ out) {
  __shared__ float r0[256], r1[256];
  int g = blockIdx.x;
  int j = threadIdx.x;
  float p = (j < DIM) ? pooled[(size_t)g * DIM + j] : 0.f;
  r0[j] = (j < DIM) ? p * w[j] : 0.f;
  r1[j] = (j < DIM) ? p * w[DIM + j] : 0.f;
  __syncthreads();
  for (int d = 128; d > 0; d >>= 1) {
    if (j < d) { r0[j] += r0[j + d]; r1[j] += r1[j + d]; }
    __syncthreads();
  }
  if (j == 0) {
    out[g * 2 + 0] = 1.f / (1.f + expf(-(r0[0] + b[0])));
    out[g * 2 + 1] = 1.f / (1.f + expf(-(r1[0] + b[1])));
  }
}

// ---------------- host ----------------
extern "C" void kernel_launch(void* const* d_in, const int* in_sizes, int n_in,
                              void* d_out, int out_size, void* d_ws, size_t ws_size,
                              hipStream_t stream) {
  const float* x = (const float*)d_in[0];
  const int* edge_index = (const int*)d_in[1];
  const int* batch = (const int*)d_in[2];
  const float* ggnn_w = (const float*)d_in[3];
  const float* w_ih = (const float*)d_in[4];
  const float* w_hh = (const float*)d_in[5];
  const float* b_ih = (const float*)d_in[6];
  const float* b_hh = (const float*)d_in[7];
  const float* cls_w = (const float*)d_in[8];
  const float* cls_b = (const float*)d_in[9];
  float* out = (float*)d_out;

  const int* src = edge_index;       // edge_index[0]
  const int* dst = edge_index + NE;  // edge_index[1]

  char* wsb = (char*)d_ws;
  size_t off = 0;
  auto alloc = [&](size_t bytes) -> void* {
    void* p = wsb + off;
    off += (bytes + 255) & ~(size_t)255;
    return p;
  };
  ushort* hHiA = (ushort*)alloc((size_t)NN * DIM * 2);   // 20 MB
  ushort* hHiB = (ushort*)alloc((size_t)NN * DIM * 2);   // 20 MB
  ushort* aggHi = (ushort*)alloc((size_t)NN * DIM * 2);  // 20 MB
  ushort* wcB = (ushort*)alloc((size_t)NSTEPS * 3 * DIM * DIM * 2);  // 1.44 MB
  ushort* whB = (ushort*)alloc((size_t)3 * DIM * DIM * 2);           // 240 KB
  ushort* bstg = (ushort*)alloc((size_t)6 * DIM * 8 * 2);            // 19.2 KB
  float* pooled = (float*)alloc((size_t)NG * DIM * 4);
  int* indeg = (int*)alloc((size_t)NN * 4);
  int* offs = (int*)alloc((size_t)(NN + 1) * 4);
  int* incl = (int*)alloc((size_t)NN * 4);
  int* bsum = (int*)alloc((size_t)256 * 4);
  int* cursor = (int*)alloc((size_t)NN * 4);
  int* slist = (int*)alloc((size_t)NE * 4);
  if (off > ws_size) return;  // fail loud (absmax) instead of faulting

  const int NB = (NN + 255) / 256;   // 196

  // h0 = bf16(x)
  k_pack_hi<<<2048, 256, 0, stream>>>(x, hHiA, NN * DIM / 8);

  // CSR build (dst -> src list)
  k_zero_i32<<<196, 256, 0, stream>>>(indeg, NN);
  k_hist<<<(NE + 255) / 256, 256, 0, stream>>>(dst, indeg, NE);
  k_scan_blk<<<NB, 256, 0, stream>>>(indeg, incl, bsum, NN);
  k_scan_top<<<1, 256, 0, stream>>>(bsum, NB);
  k_scan_fin<<<NB, 256, 0, stream>>>(indeg, incl, bsum, offs, cursor, NN);
  k_scatter<<<(NE + 255) / 256, 256, 0, stream>>>(dst, src, cursor, slist, NE);

  // weights + biases
  {
    dim3 g((3 * DIM + GBN - 1) / GBN, (DIM + GBM - 1) / GBM, NSTEPS);
    k_gemm_wc<<<g, 256, 0, stream>>>(ggnn_w, w_ih, wcB);
    k_pack_bf<<<512, 256, 0, stream>>>(w_hh, whB, 3 * DIM * DIM);
    k_prep_bias<<<5, 256, 0, stream>>>(b_ih, b_hh, bstg);
  }

  k_zero_f32<<<200, 256, 0, stream>>>(pooled, NG * DIM);

  ushort* hHic = hHiA;
  ushort* hHin = hHiB;
  for (int s = 0; s < NSTEPS; ++s) {
    k_aggregate_hi<<<(NN / 2 + 3) / 4, 256, 0, stream>>>(hHic, offs, slist, aggHi);
    k_fused_mfma<<<GRIDF, 256, 0, stream>>>(aggHi, hHic,
                                            wcB + (size_t)s * 3 * DIM * DIM,
                                            whB, bstg, hHin);
    ushort* t = hHic; hHic = hHin; hHin = t;
  }

  k_pool<<<NN, 256, 0, stream>>>(hHic, batch, pooled);
  k_classify<<<NG, 256, 0, stream>>>(pooled, cls_w, cls_b, out);
}